// Round 1
// baseline (269.004 us; speedup 1.0000x reference)
//
#include <hip/hip_runtime.h>
#include <hip/hip_bf16.h>
#include <stdint.h>

#define NTOK 4096
#define DIN  2048
#define DOUT 2048
#define RANK 16
#define NLORA 32

typedef __attribute__((ext_vector_type(4))) float f32x4;
typedef __attribute__((ext_vector_type(8))) short bf16x8;
typedef __attribute__((ext_vector_type(8))) unsigned short u16x8;

typedef const __attribute__((address_space(1))) void* gas_ptr;
typedef __attribute__((address_space(3))) void* las_ptr;

__device__ __forceinline__ unsigned short f32_to_bf16_rne(float f) {
    union { float f; unsigned int u; } v; v.f = f;
    unsigned int u = v.u;
    unsigned int r = u + 0x7fffu + ((u >> 16) & 1u);
    return (unsigned short)(r >> 16);
}
__device__ __forceinline__ float bf16_bits_to_f32(unsigned short h) {
    union { unsigned int u; float f; } v; v.u = ((unsigned int)h) << 16;
    return v.f;
}

// ---------------------------------------------------------------------------
// Split f32 -> (hi bf16, lo bf16) so that hi+lo ~= f32 (3-product MFMA GEMM).
// 8 elements / thread, fully vectorized.
// ---------------------------------------------------------------------------
__global__ __launch_bounds__(256)
void split_kernel(const float* __restrict__ in,
                  unsigned short* __restrict__ hi,
                  unsigned short* __restrict__ lo) {
    const size_t i = ((size_t)blockIdx.x * blockDim.x + threadIdx.x) * 8;
    f32x4 a = *(const f32x4*)(in + i);
    f32x4 b = *(const f32x4*)(in + i + 4);
    float f[8] = {a.x, a.y, a.z, a.w, b.x, b.y, b.z, b.w};
    u16x8 h, l;
#pragma unroll
    for (int j = 0; j < 8; j++) {
        unsigned short hb = f32_to_bf16_rne(f[j]);
        float rem = f[j] - bf16_bits_to_f32(hb);
        h[j] = hb;
        l[j] = f32_to_bf16_rne(rem);
    }
    *(u16x8*)(hi + i) = h;
    *(u16x8*)(lo + i) = l;
}

// ---------------------------------------------------------------------------
// LoRA A projection: ares[n][r] = scaling[id] * dot(x[n,:], lora_A[id,r,:])
// One wave per token; lora_A (4 MB) is L2/L3 resident.
// ---------------------------------------------------------------------------
__global__ __launch_bounds__(256)
void lora_a_kernel(const float* __restrict__ x, const int* __restrict__ ids,
                   const float* __restrict__ A, const float* __restrict__ scal,
                   float* __restrict__ ares) {
    const int wave = threadIdx.x >> 6;
    const int lane = threadIdx.x & 63;
    const int tok = blockIdx.x * 4 + wave;
    const int id = ids[tok];
    const float s = scal[id];
    const float* xr = x + (size_t)tok * DIN;
    const float* Ab = A + (size_t)id * RANK * DIN;

    float accv[RANK];
#pragma unroll
    for (int r = 0; r < RANK; r++) accv[r] = 0.f;

    for (int c = 0; c < DIN; c += 256) {                // 64 lanes x 4 floats
        const f32x4 xv = *(const f32x4*)(xr + c + lane * 4);
#pragma unroll
        for (int r = 0; r < RANK; r++) {
            const f32x4 av = *(const f32x4*)(Ab + r * DIN + c + lane * 4);
            accv[r] += xv.x * av.x + xv.y * av.y + xv.z * av.z + xv.w * av.w;
        }
    }
    float myval = 0.f;
#pragma unroll
    for (int r = 0; r < RANK; r++) {
        float v = accv[r];
#pragma unroll
        for (int off = 32; off > 0; off >>= 1) v += __shfl_xor(v, off);
        if (lane == r) myval = v;                        // static per-r select (no scratch)
    }
    if (lane < RANK) ares[(size_t)tok * RANK + lane] = myval * s;
}

// ---------------------------------------------------------------------------
// Main GEMM: out = xh/xl @ (wh/wl)^T (3-product split) + bias + Ares . loraB
// m97-style structure: 128x128 tile, BK=32, 4 waves (2x2), 16x16x32 MFMA,
// global_load_lds width=16, single LDS buffer, 2 barriers / K-step.
// ---------------------------------------------------------------------------
#define BM 128
#define BN 128
#define BK 32

__global__ __launch_bounds__(256, 2)
void gemm_lora_kernel(const unsigned short* __restrict__ Ah,
                      const unsigned short* __restrict__ Al,
                      const unsigned short* __restrict__ Wh,
                      const unsigned short* __restrict__ Wl,
                      const float* __restrict__ bias,
                      const float* __restrict__ ares,
                      const int* __restrict__ ids,
                      const float* __restrict__ loraB,
                      float* __restrict__ out) {
    __shared__ unsigned short As_h[BM * BK];
    __shared__ unsigned short As_l[BM * BK];
    __shared__ unsigned short Bs_h[BN * BK];
    __shared__ unsigned short Bs_l[BN * BK];

    const int tid = threadIdx.x;
    const int wave = tid >> 6;
    const int lane = tid & 63;
    const int wr = wave >> 1, wc = wave & 1;     // 2x2 wave grid, 64x64 each
    const int bm = blockIdx.y * BM;
    const int bn = blockIdx.x * BN;

    // staging: lane covers row q*16 + (lane>>2), 8 bf16 at col (lane&3)*8
    const int srow = lane >> 2;
    const int scol = (lane & 3) * 8;

    // fragment addressing
    const int fr = lane & 15;
    const int fq = lane >> 4;

    f32x4 acc[4][4];
#pragma unroll
    for (int i = 0; i < 4; i++)
#pragma unroll
        for (int j = 0; j < 4; j++) acc[i][j] = (f32x4){0.f, 0.f, 0.f, 0.f};

    for (int k0 = 0; k0 < DIN; k0 += BK) {
#pragma unroll
        for (int c = 0; c < 2; c++) {
            const int q = wave * 2 + c;                  // 8 chunks of 16 rows
            const int row = q * 16 + srow;
            const size_t ga = (size_t)(bm + row) * DIN + (k0 + scol);
            const size_t gb = (size_t)(bn + row) * DIN + (k0 + scol);
            const int lo = q * 16 * BK;                  // LDS elem offset (wave-uniform)
            __builtin_amdgcn_global_load_lds((gas_ptr)(Ah + ga), (las_ptr)(As_h + lo), 16, 0, 0);
            __builtin_amdgcn_global_load_lds((gas_ptr)(Al + ga), (las_ptr)(As_l + lo), 16, 0, 0);
            __builtin_amdgcn_global_load_lds((gas_ptr)(Wh + gb), (las_ptr)(Bs_h + lo), 16, 0, 0);
            __builtin_amdgcn_global_load_lds((gas_ptr)(Wl + gb), (las_ptr)(Bs_l + lo), 16, 0, 0);
        }
        __syncthreads();   // drains vmcnt before barrier (compiler-inserted)

        bf16x8 ah[4], al[4], bh[4], bl[4];
#pragma unroll
        for (int mi = 0; mi < 4; mi++) {
            const int r = (wr * 64 + mi * 16 + fr) * BK + fq * 8;
            ah[mi] = *(const bf16x8*)(As_h + r);
            al[mi] = *(const bf16x8*)(As_l + r);
        }
#pragma unroll
        for (int ni = 0; ni < 4; ni++) {
            const int r = (wc * 64 + ni * 16 + fr) * BK + fq * 8;
            bh[ni] = *(const bf16x8*)(Bs_h + r);
            bl[ni] = *(const bf16x8*)(Bs_l + r);
        }
#pragma unroll
        for (int mi = 0; mi < 4; mi++)
#pragma unroll
            for (int ni = 0; ni < 4; ni++) {
                acc[mi][ni] = __builtin_amdgcn_mfma_f32_16x16x32_bf16(ah[mi], bh[ni], acc[mi][ni], 0, 0, 0);
                acc[mi][ni] = __builtin_amdgcn_mfma_f32_16x16x32_bf16(ah[mi], bl[ni], acc[mi][ni], 0, 0, 0);
                acc[mi][ni] = __builtin_amdgcn_mfma_f32_16x16x32_bf16(al[mi], bh[ni], acc[mi][ni], 0, 0, 0);
            }
        __syncthreads();
    }

    // Epilogue: + bias + rank-16 LoRA-B dot (lora_B is 4 MB -> L2 resident).
    // C/D layout (guide-verified): col = lane&15, row = (lane>>4)*4 + reg.
#pragma unroll
    for (int mi = 0; mi < 4; mi++) {
#pragma unroll
        for (int j = 0; j < 4; j++) {
            const int n = bm + wr * 64 + mi * 16 + fq * 4 + j;
            const int id = ids[n];
            const float* ar = ares + (size_t)n * RANK;
            f32x4 a0 = *(const f32x4*)(ar);
            f32x4 a1 = *(const f32x4*)(ar + 4);
            f32x4 a2 = *(const f32x4*)(ar + 8);
            f32x4 a3 = *(const f32x4*)(ar + 12);
#pragma unroll
            for (int ni = 0; ni < 4; ni++) {
                const int o = bn + wc * 64 + ni * 16 + fr;
                const float* bp = loraB + ((size_t)id * DOUT + o) * RANK;
                f32x4 b0 = *(const f32x4*)(bp);
                f32x4 b1 = *(const f32x4*)(bp + 4);
                f32x4 b2 = *(const f32x4*)(bp + 8);
                f32x4 b3 = *(const f32x4*)(bp + 12);
                float d =
                    a0.x * b0.x + a0.y * b0.y + a0.z * b0.z + a0.w * b0.w +
                    a1.x * b1.x + a1.y * b1.y + a1.z * b1.z + a1.w * b1.w +
                    a2.x * b2.x + a2.y * b2.y + a2.z * b2.z + a2.w * b2.w +
                    a3.x * b3.x + a3.y * b3.y + a3.z * b3.z + a3.w * b3.w;
                out[(size_t)n * DOUT + o] = acc[mi][ni][j] + bias[o] + d;
            }
        }
    }
}

extern "C" void kernel_launch(void* const* d_in, const int* in_sizes, int n_in,
                              void* d_out, int out_size, void* d_ws, size_t ws_size,
                              hipStream_t stream) {
    const float* x    = (const float*)d_in[0];
    const int*   ids  = (const int*)d_in[1];
    const float* W    = (const float*)d_in[2];
    const float* bias = (const float*)d_in[3];
    const float* lA   = (const float*)d_in[4];
    const float* lB   = (const float*)d_in[5];
    const float* scal = (const float*)d_in[6];
    float* out = (float*)d_out;

    // workspace layout (~50.6 MB)
    unsigned short* x_hi = (unsigned short*)d_ws;
    unsigned short* x_lo = x_hi + (size_t)NTOK * DIN;
    unsigned short* w_hi = x_lo + (size_t)NTOK * DIN;
    unsigned short* w_lo = w_hi + (size_t)DOUT * DIN;
    float* ares = (float*)(w_lo + (size_t)DOUT * DIN);

    split_kernel<<<dim3((NTOK * DIN) / 2048), 256, 0, stream>>>(x, x_hi, x_lo);
    split_kernel<<<dim3((DOUT * DIN) / 2048), 256, 0, stream>>>(W, w_hi, w_lo);
    lora_a_kernel<<<dim3(NTOK / 4), 256, 0, stream>>>(x, ids, lA, scal, ares);
    gemm_lora_kernel<<<dim3(DOUT / BN, NTOK / BM), 256, 0, stream>>>(
        x_hi, x_lo, w_hi, w_lo, bias, ares, ids, lB, out);
}

// Round 2
// 265.166 us; speedup vs baseline: 1.0145x; 1.0145x over previous
//
#include <hip/hip_runtime.h>
#include <hip/hip_bf16.h>
#include <stdint.h>

#define NTOK 4096
#define DIN  2048
#define DOUT 2048
#define RANK 16
#define NLORA 32

typedef __attribute__((ext_vector_type(4))) float f32x4;
typedef __attribute__((ext_vector_type(8))) short bf16x8;
typedef __attribute__((ext_vector_type(8))) unsigned short u16x8;

typedef const __attribute__((address_space(1))) void* gas_ptr;
typedef __attribute__((address_space(3))) void* las_ptr;

__device__ __forceinline__ unsigned short f32_to_bf16_rne(float f) {
    union { float f; unsigned int u; } v; v.f = f;
    unsigned int u = v.u;
    unsigned int r = u + 0x7fffu + ((u >> 16) & 1u);
    return (unsigned short)(r >> 16);
}
__device__ __forceinline__ float bf16_bits_to_f32(unsigned short h) {
    union { unsigned int u; float f; } v; v.u = ((unsigned int)h) << 16;
    return v.f;
}

// ---------------------------------------------------------------------------
// Fused prep:
//   blocks [0, 2048):    split W f32 -> (hi, lo) bf16, 2048 elems/block
//   blocks [2048, 6144): one block per token: split x AND compute
//                        ares[t][r] = scal[id] * dot(x[t,:], lora_A[id,r,:])
// ---------------------------------------------------------------------------
__global__ __launch_bounds__(256)
void prep_kernel(const float* __restrict__ x, const int* __restrict__ ids,
                 const float* __restrict__ W, const float* __restrict__ lA,
                 const float* __restrict__ scal,
                 unsigned short* __restrict__ x_hi, unsigned short* __restrict__ x_lo,
                 unsigned short* __restrict__ w_hi, unsigned short* __restrict__ w_lo,
                 float* __restrict__ ares) {
    const int bid = blockIdx.x;
    if (bid < (DOUT * DIN) / 2048) {
        // ---- W split ----
        const size_t i = ((size_t)bid * 256 + threadIdx.x) * 8;
        f32x4 a = *(const f32x4*)(W + i);
        f32x4 b = *(const f32x4*)(W + i + 4);
        float f[8] = {a.x, a.y, a.z, a.w, b.x, b.y, b.z, b.w};
        u16x8 h, l;
#pragma unroll
        for (int j = 0; j < 8; j++) {
            unsigned short hb = f32_to_bf16_rne(f[j]);
            h[j] = hb;
            l[j] = f32_to_bf16_rne(f[j] - bf16_bits_to_f32(hb));
        }
        *(u16x8*)(w_hi + i) = h;
        *(u16x8*)(w_lo + i) = l;
        return;
    }
    // ---- per-token: x split + LoRA-A ----
    const int t = bid - (DOUT * DIN) / 2048;
    const int wv = threadIdx.x >> 6;
    const int lane = threadIdx.x & 63;
    const int col = wv * 512 + lane * 8;
    const int id = ids[t];
    const float s = scal[id];

    const float* xr = x + (size_t)t * DIN;
    f32x4 a = *(const f32x4*)(xr + col);
    f32x4 b = *(const f32x4*)(xr + col + 4);
    float f[8] = {a.x, a.y, a.z, a.w, b.x, b.y, b.z, b.w};
    u16x8 h, l;
#pragma unroll
    for (int j = 0; j < 8; j++) {
        unsigned short hb = f32_to_bf16_rne(f[j]);
        h[j] = hb;
        l[j] = f32_to_bf16_rne(f[j] - bf16_bits_to_f32(hb));
    }
    *(u16x8*)(x_hi + (size_t)t * DIN + col) = h;
    *(u16x8*)(x_lo + (size_t)t * DIN + col) = l;

    const float* Ar = lA + (size_t)id * RANK * DIN + col;
    __shared__ float part[4][RANK];
    float myv = 0.f;
#pragma unroll
    for (int r = 0; r < RANK; r++) {
        f32x4 va = *(const f32x4*)(Ar + (size_t)r * DIN);
        f32x4 vb = *(const f32x4*)(Ar + (size_t)r * DIN + 4);
        float v = a.x * va.x + a.y * va.y + a.z * va.z + a.w * va.w +
                  b.x * vb.x + b.y * vb.y + b.z * vb.z + b.w * vb.w;
#pragma unroll
        for (int off = 32; off > 0; off >>= 1) v += __shfl_xor(v, off);
        if (lane == r) myv = v;          // compile-time r: static select
    }
    if (lane < RANK) part[wv][lane] = myv;
    __syncthreads();
    if (threadIdx.x < RANK) {
        float sres = (part[0][threadIdx.x] + part[1][threadIdx.x]) +
                     (part[2][threadIdx.x] + part[3][threadIdx.x]);
        ares[(size_t)t * RANK + threadIdx.x] = sres * s;
    }
}

// ---------------------------------------------------------------------------
// Main GEMM, conflict-free LDS (rule #21: linear global_load_lds dest +
// inverse-swizzled per-lane GLOBAL source + swizzled ds_read).
// Combined row layout: row = 128 B = 8 chunks of 16 B; chunks 0-3 = hi k0..31,
// chunks 4-7 = lo k0..31. Chunk c stored at position p = c ^ (row&7).
// Read bank-quad = fq^(fr&7) -> each 8-lane phase covers all 8 quads (free).
// ---------------------------------------------------------------------------
#define BM 128
#define BN 128
#define BK 32

__global__ __launch_bounds__(256, 2)
void gemm_lora_kernel(const unsigned short* __restrict__ Ah,
                      const unsigned short* __restrict__ Al,
                      const unsigned short* __restrict__ Wh,
                      const unsigned short* __restrict__ Wl,
                      const float* __restrict__ bias,
                      const float* __restrict__ ares,
                      const int* __restrict__ ids,
                      const float* __restrict__ loraB,
                      float* __restrict__ out) {
    __shared__ unsigned short As[BM * 64];   // 16 KB, hi|lo combined rows
    __shared__ unsigned short Bs[BN * 64];   // 16 KB

    const int tid = threadIdx.x;
    const int wave = tid >> 6;
    const int lane = tid & 63;
    const int wr = wave >> 1, wc = wave & 1;
    const int bm = blockIdx.y * BM;
    const int bn = blockIdx.x * BN;

    // --- staging addressing (K-invariant per-lane bases) ---
    // instruction i: group g = wave*4+i covers rows [g*8, g*8+8)
    // lane -> row g*8 + (lane>>3), slot p = lane&7 holds chunk c = p ^ (row&7)
    const int rsub = lane >> 3;              // row within group, == row&7
    const int cch = (lane & 7) ^ rsub;       // source chunk 0..7
    const unsigned short* srcA[4];
    const unsigned short* srcB[4];
#pragma unroll
    for (int i = 0; i < 4; i++) {
        const int g = wave * 4 + i;
        const int row = g * 8 + rsub;
        const unsigned short* baA = (cch < 4) ? Ah : Al;
        const unsigned short* baB = (cch < 4) ? Wh : Wl;
        srcA[i] = baA + (size_t)(bm + row) * DIN + (cch & 3) * 8;
        srcB[i] = baB + (size_t)(bn + row) * DIN + (cch & 3) * 8;
    }

    // --- fragment read addressing (swizzled) ---
    const int fr = lane & 15;
    const int fq = lane >> 4;
    const int hiA_e = (wr * 64 + fr) * 64 + ((fq ^ (fr & 7)) * 8);  // elements
    const int hiB_e = (wc * 64 + fr) * 64 + ((fq ^ (fr & 7)) * 8);

    f32x4 acc[4][4];
#pragma unroll
    for (int i = 0; i < 4; i++)
#pragma unroll
        for (int j = 0; j < 4; j++) acc[i][j] = (f32x4){0.f, 0.f, 0.f, 0.f};

    for (int k0 = 0; k0 < DIN; k0 += BK) {
#pragma unroll
        for (int i = 0; i < 4; i++) {
            const int g = wave * 4 + i;
            __builtin_amdgcn_global_load_lds((gas_ptr)(srcA[i] + k0), (las_ptr)(As + g * 512), 16, 0, 0);
            __builtin_amdgcn_global_load_lds((gas_ptr)(srcB[i] + k0), (las_ptr)(Bs + g * 512), 16, 0, 0);
        }
        __syncthreads();

        bf16x8 ah[4], al[4], bh[4], bl[4];
#pragma unroll
        for (int mi = 0; mi < 4; mi++) {
            ah[mi] = *(const bf16x8*)(As + hiA_e + mi * 1024);
            al[mi] = *(const bf16x8*)(As + (hiA_e ^ 32) + mi * 1024);
        }
#pragma unroll
        for (int ni = 0; ni < 4; ni++) {
            bh[ni] = *(const bf16x8*)(Bs + hiB_e + ni * 1024);
            bl[ni] = *(const bf16x8*)(Bs + (hiB_e ^ 32) + ni * 1024);
        }
#pragma unroll
        for (int mi = 0; mi < 4; mi++)
#pragma unroll
            for (int ni = 0; ni < 4; ni++) {
                acc[mi][ni] = __builtin_amdgcn_mfma_f32_16x16x32_bf16(ah[mi], bh[ni], acc[mi][ni], 0, 0, 0);
                acc[mi][ni] = __builtin_amdgcn_mfma_f32_16x16x32_bf16(ah[mi], bl[ni], acc[mi][ni], 0, 0, 0);
                acc[mi][ni] = __builtin_amdgcn_mfma_f32_16x16x32_bf16(al[mi], bh[ni], acc[mi][ni], 0, 0, 0);
            }
        __syncthreads();
    }

    // --- epilogue: + bias + rank-16 LoRA-B dot (validated in round 1) ---
#pragma unroll
    for (int mi = 0; mi < 4; mi++) {
#pragma unroll
        for (int j = 0; j < 4; j++) {
            const int n = bm + wr * 64 + mi * 16 + fq * 4 + j;
            const int id = ids[n];
            const float* ar = ares + (size_t)n * RANK;
            f32x4 a0 = *(const f32x4*)(ar);
            f32x4 a1 = *(const f32x4*)(ar + 4);
            f32x4 a2 = *(const f32x4*)(ar + 8);
            f32x4 a3 = *(const f32x4*)(ar + 12);
#pragma unroll
            for (int ni = 0; ni < 4; ni++) {
                const int o = bn + wc * 64 + ni * 16 + fr;
                const float* bp = loraB + ((size_t)id * DOUT + o) * RANK;
                f32x4 b0 = *(const f32x4*)(bp);
                f32x4 b1 = *(const f32x4*)(bp + 4);
                f32x4 b2 = *(const f32x4*)(bp + 8);
                f32x4 b3 = *(const f32x4*)(bp + 12);
                float d =
                    a0.x * b0.x + a0.y * b0.y + a0.z * b0.z + a0.w * b0.w +
                    a1.x * b1.x + a1.y * b1.y + a1.z * b1.z + a1.w * b1.w +
                    a2.x * b2.x + a2.y * b2.y + a2.z * b2.z + a2.w * b2.w +
                    a3.x * b3.x + a3.y * b3.y + a3.z * b3.z + a3.w * b3.w;
                out[(size_t)n * DOUT + o] = acc[mi][ni][j] + bias[o] + d;
            }
        }
    }
}

extern "C" void kernel_launch(void* const* d_in, const int* in_sizes, int n_in,
                              void* d_out, int out_size, void* d_ws, size_t ws_size,
                              hipStream_t stream) {
    const float* x    = (const float*)d_in[0];
    const int*   ids  = (const int*)d_in[1];
    const float* W    = (const float*)d_in[2];
    const float* bias = (const float*)d_in[3];
    const float* lA   = (const float*)d_in[4];
    const float* lB   = (const float*)d_in[5];
    const float* scal = (const float*)d_in[6];
    float* out = (float*)d_out;

    unsigned short* x_hi = (unsigned short*)d_ws;
    unsigned short* x_lo = x_hi + (size_t)NTOK * DIN;
    unsigned short* w_hi = x_lo + (size_t)NTOK * DIN;
    unsigned short* w_lo = w_hi + (size_t)DOUT * DIN;
    float* ares = (float*)(w_lo + (size_t)DOUT * DIN);

    prep_kernel<<<dim3((DOUT * DIN) / 2048 + NTOK), 256, 0, stream>>>(
        x, ids, W, lA, scal, x_hi, x_lo, w_hi, w_lo, ares);
    gemm_lora_kernel<<<dim3(DOUT / BN, NTOK / BM), 256, 0, stream>>>(
        x_hi, x_lo, w_hi, w_lo, bias, ares, ids, lB, out);
}